// Round 4
// baseline (47.173 us; speedup 1.0000x reference)
//
#include <hip/hip_runtime.h>
#include <hip/hip_bf16.h>

#define NEG_SLOPE 0.2f

// Clang native vectors — required for __builtin_nontemporal_* (HIP_vector_type
// float4/int4 are C++ classes and are rejected by the builtin).
typedef float f32x4 __attribute__((ext_vector_type(4)));
typedef int   i32x4 __attribute__((ext_vector_type(4)));

// ---------------------------------------------------------------------------
// Fused node kernel.
// Stage 1 (per block, redundant): fold GAT attention vectors through the
//   projection into LDS: v1 = W^T a[:64], v2 = W^T a[64:], per channel.
//   vsh[0]=v1_b, vsh[1]=v2_b, vsh[2]=v1_p, vsh[3]=v2_p. W is 64 KB total and
//   L2-resident, so 2048 blocks re-reading it is ~free.
// Stage 2: one wave processes TWO nodes per iteration: lane = 32*h + c; half
//   h owns node 2*pr+h, lane loads f32x4 at column 4c (16 B/lane). 5-step
//   butterfly within each 32-lane half. tab[n] = (si_b, sj_b, si_p, sj_p).
// ---------------------------------------------------------------------------
__global__ void __launch_bounds__(256) node_scores_kernel(
        const float*  __restrict__ W_b,
        const float*  __restrict__ W_p,
        const float*  __restrict__ a_b,
        const float*  __restrict__ a_p,
        const f32x4*  __restrict__ zb4,
        const f32x4*  __restrict__ zp4,
        f32x4*        __restrict__ tab,
        int n_nodes) {
    __shared__ float vsh[4][128];

    const int t = threadIdx.x;
    {
        const int p    = t & 127;
        const int half = t >> 7;               // 0: a[0:64], 1: a[64:128]
        const float* ab = a_b + 64 * half;
        const float* ap = a_p + 64 * half;
        float accb = 0.f, accp = 0.f;
        #pragma unroll
        for (int d = 0; d < 64; ++d) {
            accb += W_b[d * 128 + p] * ab[d];
            accp += W_p[d * 128 + p] * ap[d];
        }
        vsh[half][p]     = accb;               // v1_b / v2_b
        vsh[2 + half][p] = accp;               // v1_p / v2_p
    }
    __syncthreads();

    const int lane = t & 63;
    const int h    = lane >> 5;                // which node of the pair
    const int c    = lane & 31;                // f32x4 column group
    const int wave   = (blockIdx.x * blockDim.x + t) >> 6;
    const int nwaves = (gridDim.x * blockDim.x) >> 6;
    const int npairs = (n_nodes + 1) >> 1;

    const f32x4 v1b = *reinterpret_cast<const f32x4*>(&vsh[0][4 * c]);
    const f32x4 v2b = *reinterpret_cast<const f32x4*>(&vsh[1][4 * c]);
    const f32x4 v1p = *reinterpret_cast<const f32x4*>(&vsh[2][4 * c]);
    const f32x4 v2p = *reinterpret_cast<const f32x4*>(&vsh[3][4 * c]);

    for (int pr = wave; pr < npairs; pr += nwaves) {
        int node = 2 * pr + h;
        const int valid = node < n_nodes;
        if (!valid) node = n_nodes - 1;        // safe clamp (n even in practice)
        const size_t base = (size_t)node * 32 + c;
        const f32x4 zb = __builtin_nontemporal_load(&zb4[base]);
        const f32x4 zp = __builtin_nontemporal_load(&zp4[base]);
        float sib = zb.x * v1b.x + zb.y * v1b.y + zb.z * v1b.z + zb.w * v1b.w;
        float sjb = zb.x * v2b.x + zb.y * v2b.y + zb.z * v2b.z + zb.w * v2b.w;
        float sip = zp.x * v1p.x + zp.y * v1p.y + zp.z * v1p.z + zp.w * v1p.w;
        float sjp = zp.x * v2p.x + zp.y * v2p.y + zp.z * v2p.z + zp.w * v2p.w;
        #pragma unroll
        for (int off = 16; off > 0; off >>= 1) {   // stays within 32-lane half
            sib += __shfl_xor(sib, off);
            sjb += __shfl_xor(sjb, off);
            sip += __shfl_xor(sip, off);
            sjp += __shfl_xor(sjp, off);
        }
        if (c == 0 && valid) {
            f32x4 r;
            r.x = sib; r.y = sjb; r.z = sip; r.w = sjp;
            tab[node] = r;                     // keep in L2 for edge phase
        }
    }
}

// ---------------------------------------------------------------------------
// Edge kernel: 4 edges per thread. i32x4 index loads (16 B/lane), f32x4 out
// store, nontemporal on the streaming operands so tab stays L2-resident.
// ---------------------------------------------------------------------------
__device__ __forceinline__ float lrelu(float x) {
    return x >= 0.f ? x : NEG_SLOPE * x;
}

__device__ __forceinline__ float edge_score(const f32x4 ts, const f32x4 td,
                                            float w0, float w1) {
    const float sb = 0.5f * (lrelu(ts.x + td.y) + lrelu(td.x + ts.y));
    const float sp = 0.5f * (lrelu(ts.z + td.w) + lrelu(td.z + ts.w));
    const float sc = w0 * sb + w1 * sp;            // TAU_MRF == 1
    return 1.f / (1.f + __expf(-sc));
}

__global__ void __launch_bounds__(256) edge_scores_kernel(
        const int*    __restrict__ src,
        const int*    __restrict__ dst,
        const f32x4*  __restrict__ tab,
        const float*  __restrict__ gamma_b,
        const float*  __restrict__ gamma_p,
        float*        __restrict__ out,
        int n_edges) {
    const float gb = *gamma_b;
    const float gp = *gamma_p;
    const float w0 = 1.f / (1.f + __expf(gp - gb));  // softmax over 2 logits
    const float w1 = 1.f - w0;

    const int n_quads = n_edges >> 2;
    const int stride  = gridDim.x * blockDim.x;
    const int gid     = blockIdx.x * blockDim.x + threadIdx.x;

    const i32x4* src4 = (const i32x4*)src;
    const i32x4* dst4 = (const i32x4*)dst;
    f32x4*       out4 = (f32x4*)out;

    for (int i = gid; i < n_quads; i += stride) {
        const i32x4 s = __builtin_nontemporal_load(&src4[i]);
        const i32x4 d = __builtin_nontemporal_load(&dst4[i]);
        f32x4 r;
        r.x = edge_score(tab[s.x], tab[d.x], w0, w1);
        r.y = edge_score(tab[s.y], tab[d.y], w0, w1);
        r.z = edge_score(tab[s.z], tab[d.z], w0, w1);
        r.w = edge_score(tab[s.w], tab[d.w], w0, w1);
        __builtin_nontemporal_store(r, &out4[i]);
    }
    // tail (n_edges % 4 != 0) — unused for E = 1e6 but kept for safety
    const int tail_base = n_quads << 2;
    for (int e = tail_base + gid; e < n_edges; e += stride) {
        out[e] = edge_score(tab[src[e]], tab[dst[e]], w0, w1);
    }
}

extern "C" void kernel_launch(void* const* d_in, const int* in_sizes, int n_in,
                              void* d_out, int out_size, void* d_ws, size_t ws_size,
                              hipStream_t stream) {
    const float* z_beh  = (const float*)d_in[0];
    const float* z_pref = (const float*)d_in[1];
    const float* W_b    = (const float*)d_in[2];
    const float* W_p    = (const float*)d_in[3];
    const float* a_b    = (const float*)d_in[4];
    const float* a_p    = (const float*)d_in[5];
    const float* g_b    = (const float*)d_in[6];
    const float* g_p    = (const float*)d_in[7];
    const int*   ei     = (const int*)d_in[8];   // [2, E] int32

    const int n_nodes = in_sizes[0] / 128;
    const int n_edges = in_sizes[8] / 2;

    f32x4* tab = (f32x4*)d_ws;                   // n_nodes f32x4

    // 2048 blocks x 4 waves = 8192 waves (full residency), 2 nodes/wave/iter
    node_scores_kernel<<<2048, 256, 0, stream>>>(
        W_b, W_p, a_b, a_p,
        (const f32x4*)z_beh, (const f32x4*)z_pref, tab, n_nodes);

    const int n_quads = n_edges >> 2;
    int eblocks = (n_quads + 255) / 256;
    if (eblocks > 2048) eblocks = 2048;
    if (eblocks < 1) eblocks = 1;
    edge_scores_kernel<<<eblocks, 256, 0, stream>>>(
        ei, ei + n_edges, tab, g_b, g_p, (float*)d_out, n_edges);
}

// Round 5
// 38.609 us; speedup vs baseline: 1.2218x; 1.2218x over previous
//
#include <hip/hip_runtime.h>
#include <hip/hip_bf16.h>

#define NEG_SLOPE 0.2f

typedef float f32x4 __attribute__((ext_vector_type(4)));
typedef int   i32x4 __attribute__((ext_vector_type(4)));

// ---------------------------------------------------------------------------
// Kernel A: fold GAT attention vectors through the projection.
// v layout: [4][128] = v1_b, v2_b, v1_p, v2_p  (v1 = W^T a[:64], v2 = W^T a[64:])
// 256 threads: t<128 -> channel b, t>=128 -> channel p; d-loop fully unrolled.
// ---------------------------------------------------------------------------
__global__ void compute_v_kernel(const float* __restrict__ W_b,
                                 const float* __restrict__ W_p,
                                 const float* __restrict__ a_b,
                                 const float* __restrict__ a_p,
                                 float* __restrict__ v) {
    const int t  = threadIdx.x;          // 0..255
    const int p  = t & 127;
    const int ch = t >> 7;               // 0 = behavior, 1 = preference
    const float* W = ch ? W_p : W_b;
    const float* a = ch ? a_p : a_b;
    float acc1 = 0.f, acc2 = 0.f;
    #pragma unroll
    for (int d = 0; d < 64; ++d) {
        const float w = W[d * 128 + p];
        acc1 += w * a[d];
        acc2 += w * a[64 + d];
    }
    v[(2 * ch + 0) * 128 + p] = acc1;
    v[(2 * ch + 1) * 128 + p] = acc2;
}

// ---------------------------------------------------------------------------
// Kernel B: per-node scalars. One wave = TWO nodes per iteration (lane =
// 32*h + c). 16 B/lane float4 loads (wave covers 1 KB contiguous per array).
// Folded reduction: 6 shuffles total instead of 20.
//   fold@16: lanes c<16 accumulate channel-b, c>=16 channel-p (2 shuffles)
//   fold@8 : c&8==0 keep i-slot, c&8==1 keep j-slot          (1 shuffle)
//   plain butterfly over offsets 4,2,1                        (3 shuffles)
// Lane c%8==0 then holds scalar (c>>3) of float4(si_b,sj_b,si_p,sj_p).
// ---------------------------------------------------------------------------
__global__ void __launch_bounds__(256) node_scores_kernel(
        const f32x4* __restrict__ zb4,
        const f32x4* __restrict__ zp4,
        const float* __restrict__ v,
        float*       __restrict__ tab,   // float view of [n_nodes][4]
        int n_nodes) {
    const int t    = threadIdx.x;
    const int lane = t & 63;
    const int h    = lane >> 5;                // which node of the pair
    const int c    = lane & 31;                // float4 column group
    const int wave   = (blockIdx.x * blockDim.x + t) >> 6;
    const int nwaves = (gridDim.x * blockDim.x) >> 6;
    const int npairs = (n_nodes + 1) >> 1;

    const f32x4 v1b = *reinterpret_cast<const f32x4*>(v + 0 * 128 + 4 * c);
    const f32x4 v2b = *reinterpret_cast<const f32x4*>(v + 1 * 128 + 4 * c);
    const f32x4 v1p = *reinterpret_cast<const f32x4*>(v + 2 * 128 + 4 * c);
    const f32x4 v2p = *reinterpret_cast<const f32x4*>(v + 3 * 128 + 4 * c);

    const bool hiB = (c & 16) != 0;
    const bool hiJ = (c & 8)  != 0;

    for (int pr = wave; pr < npairs; pr += nwaves) {
        int node = 2 * pr + h;
        const int valid = node < n_nodes;
        if (!valid) node = n_nodes - 1;        // safe clamp (N is even here)
        const size_t base = (size_t)node * 32 + c;
        const f32x4 zb = zb4[base];
        const f32x4 zp = zp4[base];
        float sib = zb.x * v1b.x + zb.y * v1b.y + zb.z * v1b.z + zb.w * v1b.w;
        float sjb = zb.x * v2b.x + zb.y * v2b.y + zb.z * v2b.z + zb.w * v2b.w;
        float sip = zp.x * v1p.x + zp.y * v1p.y + zp.z * v1p.z + zp.w * v1p.w;
        float sjp = zp.x * v2p.x + zp.y * v2p.y + zp.z * v2p.z + zp.w * v2p.w;

        // fold @16: lo half of 32-group keeps b-channel, hi half keeps p
        float g1 = hiB ? sib : sip;
        float r1 = __shfl_xor(g1, 16);
        float acc_i = (hiB ? sip : sib) + r1;
        float g2 = hiB ? sjb : sjp;
        float r2 = __shfl_xor(g2, 16);
        float acc_j = (hiB ? sjp : sjb) + r2;

        // fold @8: c&8==0 keeps i-slot, c&8==1 keeps j-slot
        float g3 = hiJ ? acc_i : acc_j;
        float r3 = __shfl_xor(g3, 8);
        float acc = (hiJ ? acc_j : acc_i) + r3;

        // plain butterfly within 8-lane groups
        acc += __shfl_xor(acc, 4);
        acc += __shfl_xor(acc, 2);
        acc += __shfl_xor(acc, 1);

        if ((c & 7) == 0 && valid) {
            tab[(size_t)node * 4 + (c >> 3)] = acc;
        }
    }
}

// ---------------------------------------------------------------------------
// Kernel C: per-edge, 4 edges per thread. int4 index loads (16 B/lane),
// float4 output store. tab (1.6 MB) is L2-resident; gathers hit L2.
// ---------------------------------------------------------------------------
__device__ __forceinline__ float lrelu(float x) {
    return x >= 0.f ? x : NEG_SLOPE * x;
}

__device__ __forceinline__ float edge_score(const f32x4 ts, const f32x4 td,
                                            float w0, float w1) {
    const float sb = 0.5f * (lrelu(ts.x + td.y) + lrelu(td.x + ts.y));
    const float sp = 0.5f * (lrelu(ts.z + td.w) + lrelu(td.z + ts.w));
    const float sc = w0 * sb + w1 * sp;            // TAU_MRF == 1
    return 1.f / (1.f + __expf(-sc));
}

__global__ void __launch_bounds__(256) edge_scores_kernel(
        const int*   __restrict__ src,
        const int*   __restrict__ dst,
        const f32x4* __restrict__ tab,
        const float* __restrict__ gamma_b,
        const float* __restrict__ gamma_p,
        float*       __restrict__ out,
        int n_edges) {
    const float gb = *gamma_b;
    const float gp = *gamma_p;
    const float w0 = 1.f / (1.f + __expf(gp - gb));  // softmax over 2 logits
    const float w1 = 1.f - w0;

    const int n_quads = n_edges >> 2;
    const int stride  = gridDim.x * blockDim.x;
    const int gid     = blockIdx.x * blockDim.x + threadIdx.x;

    const i32x4* src4 = (const i32x4*)src;
    const i32x4* dst4 = (const i32x4*)dst;
    f32x4*       out4 = (f32x4*)out;

    for (int i = gid; i < n_quads; i += stride) {
        const i32x4 s = src4[i];
        const i32x4 d = dst4[i];
        f32x4 r;
        r.x = edge_score(tab[s.x], tab[d.x], w0, w1);
        r.y = edge_score(tab[s.y], tab[d.y], w0, w1);
        r.z = edge_score(tab[s.z], tab[d.z], w0, w1);
        r.w = edge_score(tab[s.w], tab[d.w], w0, w1);
        out4[i] = r;
    }
    // tail (n_edges % 4 != 0) — unused for E = 1e6 but kept for safety
    const int tail_base = n_quads << 2;
    for (int e = tail_base + gid; e < n_edges; e += stride) {
        out[e] = edge_score(tab[src[e]], tab[dst[e]], w0, w1);
    }
}

extern "C" void kernel_launch(void* const* d_in, const int* in_sizes, int n_in,
                              void* d_out, int out_size, void* d_ws, size_t ws_size,
                              hipStream_t stream) {
    const float* z_beh  = (const float*)d_in[0];
    const float* z_pref = (const float*)d_in[1];
    const float* W_b    = (const float*)d_in[2];
    const float* W_p    = (const float*)d_in[3];
    const float* a_b    = (const float*)d_in[4];
    const float* a_p    = (const float*)d_in[5];
    const float* g_b    = (const float*)d_in[6];
    const float* g_p    = (const float*)d_in[7];
    const int*   ei     = (const int*)d_in[8];   // [2, E] int32

    const int n_nodes = in_sizes[0] / 128;
    const int n_edges = in_sizes[8] / 2;

    float* v   = (float*)d_ws;                       // 512 floats
    float* tab = (float*)((char*)d_ws + 2048);       // n_nodes * 4 floats

    compute_v_kernel<<<1, 256, 0, stream>>>(W_b, W_p, a_b, a_p, v);

    // 2048 blocks x 4 waves = 8192 waves (full residency), 2 nodes/wave/iter
    node_scores_kernel<<<2048, 256, 0, stream>>>(
        (const f32x4*)z_beh, (const f32x4*)z_pref, v, tab, n_nodes);

    const int n_quads = n_edges >> 2;
    int eblocks = (n_quads + 255) / 256;
    if (eblocks > 2048) eblocks = 2048;
    if (eblocks < 1) eblocks = 1;
    edge_scores_kernel<<<eblocks, 256, 0, stream>>>(
        ei, ei + n_edges, (const f32x4*)tab, g_b, g_p, (float*)d_out, n_edges);
}

// Round 6
// 36.146 us; speedup vs baseline: 1.3051x; 1.0681x over previous
//
#include <hip/hip_runtime.h>
#include <hip/hip_bf16.h>

#define NEG_SLOPE 0.2f

typedef float f32x4 __attribute__((ext_vector_type(4)));

// ---------------------------------------------------------------------------
// Folded 64-lane reduction (6 shuffles). Input: per-lane partial dot products
// for (si_b, sj_b, si_p, sj_p) of one node (32 lanes per node).
//   fold@16: lanes c<16 keep channel-b, c>=16 channel-p
//   fold@8 : c&8==0 keeps i-slot, c&8==1 keeps j-slot
//   butterfly 4,2,1. Lane c%8==0 holds component (c>>3) of the node's float4.
// ---------------------------------------------------------------------------
__device__ __forceinline__ float fold_reduce(float sib, float sjb,
                                             float sip, float sjp,
                                             bool hiB, bool hiJ) {
    float g1 = hiB ? sib : sip;
    float r1 = __shfl_xor(g1, 16);
    float acc_i = (hiB ? sip : sib) + r1;
    float g2 = hiB ? sjb : sjp;
    float r2 = __shfl_xor(g2, 16);
    float acc_j = (hiB ? sjp : sjb) + r2;
    float g3 = hiJ ? acc_i : acc_j;
    float r3 = __shfl_xor(g3, 8);
    float acc = (hiJ ? acc_j : acc_i) + r3;
    acc += __shfl_xor(acc, 4);
    acc += __shfl_xor(acc, 2);
    acc += __shfl_xor(acc, 1);
    return acc;
}

__device__ __forceinline__ float dot4(const f32x4 z, const f32x4 v) {
    return z.x * v.x + z.y * v.y + z.z * v.z + z.w * v.w;
}

// ---------------------------------------------------------------------------
// Fused kernel: v-fold prologue (per block, in LDS) + node score stream.
// 512 blocks x 1024 threads = exactly resident (2 blocks/CU), so the
// prologue runs concurrently everywhere: 512 x 64KB = 32 MB of L2 W-traffic
// (~1 us aggregate) instead of a separate latency-bound dispatch + gap.
// Main loop: wave = 2 nodes/iter (lane = 32h + c, 16 B/lane), 2-pair unroll.
// ---------------------------------------------------------------------------
__global__ void __launch_bounds__(1024) fused_node_kernel(
        const float* __restrict__ W_b,
        const float* __restrict__ W_p,
        const float* __restrict__ a_b,
        const float* __restrict__ a_p,
        const f32x4* __restrict__ zb4,
        const f32x4* __restrict__ zp4,
        float*       __restrict__ tab,   // float view of [n_nodes][4]
        int n_nodes) {
    __shared__ float vsh[4][128];   // v1_b, v2_b, v1_p, v2_p
    __shared__ float psh[1024];

    const int tid = threadIdx.x;
    {   // prologue: vsh[vec][p] = sum_d W_ch[d][p] * a_ch[aoff + d]
        const int q   = tid >> 9;        // d-half (0: d<32, 1: d>=32)
        const int r   = tid & 511;       // output index (vec*128 + p)
        const int vec = r >> 7;
        const int p   = r & 127;
        const float* W = (vec >= 2) ? W_p : W_b;
        const float* a = ((vec >= 2) ? a_p : a_b) + (vec & 1) * 64 + 32 * q;
        const float* Wc = W + (32 * q) * 128 + p;
        float acc = 0.f;
        #pragma unroll
        for (int k = 0; k < 32; ++k)
            acc += Wc[k * 128] * a[k];
        psh[tid] = acc;
    }
    __syncthreads();
    if (tid < 512)
        vsh[tid >> 7][tid & 127] = psh[tid] + psh[512 + tid];
    __syncthreads();

    const int lane = tid & 63;
    const int h    = lane >> 5;                 // which node of the pair
    const int c    = lane & 31;                 // f32x4 column group
    const int wave   = (blockIdx.x * blockDim.x + tid) >> 6;
    const int nwaves = (gridDim.x * blockDim.x) >> 6;   // 8192
    const int npairs = (n_nodes + 1) >> 1;

    const f32x4 v1b = *reinterpret_cast<const f32x4*>(&vsh[0][4 * c]);
    const f32x4 v2b = *reinterpret_cast<const f32x4*>(&vsh[1][4 * c]);
    const f32x4 v1p = *reinterpret_cast<const f32x4*>(&vsh[2][4 * c]);
    const f32x4 v2p = *reinterpret_cast<const f32x4*>(&vsh[3][4 * c]);

    const bool hiB = (c & 16) != 0;
    const bool hiJ = (c & 8)  != 0;
    const bool wr  = (c & 7) == 0;
    const int  comp = c >> 3;

    for (int pr = wave; pr < npairs; pr += 2 * nwaves) {
        const int pr2 = pr + nwaves;
        // --- pair 1 ---
        int node1 = 2 * pr + h;
        const bool valid1 = node1 < n_nodes;
        if (!valid1) node1 = n_nodes - 1;
        const f32x4 zb1 = zb4[node1 * 32 + c];
        const f32x4 zp1 = zp4[node1 * 32 + c];
        // --- pair 2 (loads issued before reductions for MLP) ---
        int node2 = 2 * pr2 + h;
        const bool run2   = pr2 < npairs;
        bool valid2 = run2 && (node2 < n_nodes);
        if (!valid2) node2 = n_nodes - 1;
        const f32x4 zb2 = zb4[node2 * 32 + c];
        const f32x4 zp2 = zp4[node2 * 32 + c];

        float acc1 = fold_reduce(dot4(zb1, v1b), dot4(zb1, v2b),
                                 dot4(zp1, v1p), dot4(zp1, v2p), hiB, hiJ);
        if (wr && valid1) tab[node1 * 4 + comp] = acc1;

        float acc2 = fold_reduce(dot4(zb2, v1b), dot4(zb2, v2b),
                                 dot4(zp2, v1p), dot4(zp2, v2p), hiB, hiJ);
        if (wr && valid2) tab[node2 * 4 + comp] = acc2;
    }
}

// ---------------------------------------------------------------------------
// Edge kernel: 2 edges per thread (int2 indices, float2 out) -> 1954 blocks
// (~7.6 blocks/CU) for gather-latency hiding. tab (1.6 MB) is L2-resident.
// ---------------------------------------------------------------------------
__device__ __forceinline__ float lrelu(float x) {
    return x >= 0.f ? x : NEG_SLOPE * x;
}

__device__ __forceinline__ float edge_score(const f32x4 ts, const f32x4 td,
                                            float w0, float w1) {
    const float sb = 0.5f * (lrelu(ts.x + td.y) + lrelu(td.x + ts.y));
    const float sp = 0.5f * (lrelu(ts.z + td.w) + lrelu(td.z + ts.w));
    const float sc = w0 * sb + w1 * sp;            // TAU_MRF == 1
    return 1.f / (1.f + __expf(-sc));
}

__global__ void __launch_bounds__(256) edge_scores_kernel(
        const int*   __restrict__ src,
        const int*   __restrict__ dst,
        const f32x4* __restrict__ tab,
        const float* __restrict__ gamma_b,
        const float* __restrict__ gamma_p,
        float*       __restrict__ out,
        int n_edges) {
    const float gb = *gamma_b;
    const float gp = *gamma_p;
    const float w0 = 1.f / (1.f + __expf(gp - gb));  // softmax over 2 logits
    const float w1 = 1.f - w0;

    const int n_half = n_edges >> 1;
    const int stride = gridDim.x * blockDim.x;
    const int gid    = blockIdx.x * blockDim.x + threadIdx.x;

    const int2* src2 = (const int2*)src;
    const int2* dst2 = (const int2*)dst;
    float2*     out2 = (float2*)out;

    for (int i = gid; i < n_half; i += stride) {
        const int2 s = src2[i];
        const int2 d = dst2[i];
        const f32x4 ts0 = tab[s.x];
        const f32x4 td0 = tab[d.x];
        const f32x4 ts1 = tab[s.y];
        const f32x4 td1 = tab[d.y];
        float2 r;
        r.x = edge_score(ts0, td0, w0, w1);
        r.y = edge_score(ts1, td1, w0, w1);
        out2[i] = r;
    }
    // tail (odd n_edges) — unused for E = 1e6 but kept for safety
    const int tail_base = n_half << 1;
    for (int e = tail_base + gid; e < n_edges; e += stride) {
        out[e] = edge_score(tab[src[e]], tab[dst[e]], w0, w1);
    }
}

extern "C" void kernel_launch(void* const* d_in, const int* in_sizes, int n_in,
                              void* d_out, int out_size, void* d_ws, size_t ws_size,
                              hipStream_t stream) {
    const float* z_beh  = (const float*)d_in[0];
    const float* z_pref = (const float*)d_in[1];
    const float* W_b    = (const float*)d_in[2];
    const float* W_p    = (const float*)d_in[3];
    const float* a_b    = (const float*)d_in[4];
    const float* a_p    = (const float*)d_in[5];
    const float* g_b    = (const float*)d_in[6];
    const float* g_p    = (const float*)d_in[7];
    const int*   ei     = (const int*)d_in[8];   // [2, E] int32

    const int n_nodes = in_sizes[0] / 128;
    const int n_edges = in_sizes[8] / 2;

    float* tab = (float*)d_ws;                   // n_nodes * 4 floats

    // 512 blocks x 1024 threads: exactly resident, 8192 waves
    fused_node_kernel<<<512, 1024, 0, stream>>>(
        W_b, W_p, a_b, a_p,
        (const f32x4*)z_beh, (const f32x4*)z_pref, tab, n_nodes);

    const int n_half = n_edges >> 1;
    int eblocks = (n_half + 255) / 256;
    if (eblocks > 4096) eblocks = 4096;
    if (eblocks < 1) eblocks = 1;
    edge_scores_kernel<<<eblocks, 256, 0, stream>>>(
        ei, ei + n_edges, (const f32x4*)tab, g_b, g_p, (float*)d_out, n_edges);
}